// Round 1
// baseline (2077.243 us; speedup 1.0000x reference)
//
#include <hip/hip_runtime.h>

typedef _Float16 f16;
typedef _Float16 f16x2 __attribute__((ext_vector_type(2)));
typedef _Float16 f16x8 __attribute__((ext_vector_type(8)));
typedef float    f32x4 __attribute__((ext_vector_type(4)));
typedef unsigned int u32x4 __attribute__((ext_vector_type(4)));

// ---------- helpers ----------
__device__ __forceinline__ float dot2u(unsigned a, unsigned b, float c){
  return __builtin_amdgcn_fdot2(__builtin_bit_cast(f16x2, a),
                                __builtin_bit_cast(f16x2, b), c, false);
}
__device__ __forceinline__ float sigm(float x){ return 1.0f/(1.0f+__expf(-x)); }
__device__ __forceinline__ float tanh_(float x){
  x = fminf(fmaxf(x, -20.f), 20.f);
  return 1.0f - 2.0f/(__expf(2.0f*x)+1.0f);
}

// ---------- K0: fp32 -> f16 convert (8 elems/thread) ----------
__global__ void k_cvt(const float* __restrict__ src, f16* __restrict__ dst, int n){
  int i = (blockIdx.x*256 + threadIdx.x)*8;
  if (i >= n) return;
  float4 a = *(const float4*)(src + i);
  float4 b = *(const float4*)(src + i + 4);
  f16x8 o;
  o[0]=(f16)a.x; o[1]=(f16)a.y; o[2]=(f16)a.z; o[3]=(f16)a.w;
  o[4]=(f16)b.x; o[5]=(f16)b.y; o[6]=(f16)b.z; o[7]=(f16)b.w;
  *(f16x8*)(dst+i) = o;
}

// ---------- K0c: pack W_hh (both dirs) into per-thread-coalesced u32x4 layout ----------
// layout: idx = ((dir*4+g)*32+jj)*256 + t ; covers k = 8*jj .. 8*jj+7 of row g*256+t
__global__ void k_wpack(const float* __restrict__ whf, const float* __restrict__ whb,
                        u32x4* __restrict__ wp){
  int idx = blockIdx.x*256 + threadIdx.x;     // 0..65535
  int t   = idx & 255;
  int jj  = (idx >> 8) & 31;
  int g   = (idx >> 13) & 3;
  int dir = (idx >> 15) & 1;
  const float* w = dir ? whb : whf;
  const float* row = w + (g*256 + t)*256 + jj*8;
  u32x4 v;
  #pragma unroll
  for (int q=0;q<4;q++){
    f16x2 h2; h2[0] = (f16)row[2*q]; h2[1] = (f16)row[2*q+1];
    v[q] = __builtin_bit_cast(unsigned, h2);
  }
  wp[idx] = v;
}

// ---------- K1: gx = X(32768x768) @ Wcat(2048x768)^T  (f16 out, fp32 acc MFMA) ----------
__global__ __launch_bounds__(256) void k_gemm(const f16* __restrict__ A,
                                              const f16* __restrict__ Bw,
                                              f16* __restrict__ C){
  __shared__ alignas(16) f16 As[128][64];
  __shared__ alignas(16) f16 Bs[128][64];
  int bid = blockIdx.x;
  int bm = bid >> 4, bn = bid & 15;
  int tid = threadIdx.x;
  int w = tid >> 6, l = tid & 63;
  int wm = w >> 1, wn = w & 1;
  f32x4 acc[4][4] = {};
  int srow = tid >> 3;
  int scol = (tid & 7)*8;
  const f16* Ag = A  + (size_t)(bm*128)*768 + scol;
  const f16* Bg = Bw + (size_t)(bn*128)*768 + scol;
  int fr = l & 15, kg = l >> 4;
  for (int k0 = 0; k0 < 768; k0 += 64){
    #pragma unroll
    for (int q=0;q<4;q++){
      int rr = srow + 32*q;
      u32x4 av = *(const u32x4*)(Ag + rr*768 + k0);
      u32x4 bv = *(const u32x4*)(Bg + rr*768 + k0);
      *(u32x4*)&As[rr][scol] = av;
      *(u32x4*)&Bs[rr][scol] = bv;
    }
    __syncthreads();
    #pragma unroll
    for (int ks=0; ks<2; ks++){
      f16x8 af[4], bf[4];
      #pragma unroll
      for (int mi=0;mi<4;mi++) af[mi] = *(const f16x8*)&As[wm*64+mi*16+fr][ks*32+kg*8];
      #pragma unroll
      for (int ni=0;ni<4;ni++) bf[ni] = *(const f16x8*)&Bs[wn*64+ni*16+fr][ks*32+kg*8];
      #pragma unroll
      for (int mi=0;mi<4;mi++)
        #pragma unroll
        for (int ni=0;ni<4;ni++)
          acc[mi][ni] = __builtin_amdgcn_mfma_f32_16x16x32_f16(af[mi], bf[ni], acc[mi][ni], 0,0,0);
    }
    __syncthreads();
  }
  int fq = l >> 4;
  #pragma unroll
  for (int mi=0;mi<4;mi++)
    #pragma unroll
    for (int ni=0;ni<4;ni++){
      int mrow = bm*128 + wm*64 + mi*16 + fq*4;
      int ncol = bn*128 + wn*64 + ni*16 + fr;
      #pragma unroll
      for (int r=0;r<4;r++)
        C[(size_t)(mrow+r)*2048 + ncol] = (f16)acc[mi][ni][r];
    }
}

// ---------- K2: recurrence. One block per (batch,dir) chain; thread u = hidden unit u ----------
__global__ __launch_bounds__(256,1) void k_rnn(const u32x4* __restrict__ wp,
            const f16* __restrict__ gx, const float* __restrict__ bfp,
            const float* __restrict__ bbp, f16* __restrict__ Hc){
  __shared__ u32x4 lwt[4][8][256];          // 128 KB weight tail (k = 192..255)
  __shared__ alignas(16) f16 lh[2][256];    // h double buffer
  int chain = blockIdx.x;
  int b = chain >> 1, dir = chain & 1;
  int u = threadIdx.x;
  const u32x4* wpd = wp + dir*32768;
  u32x4 w[4][24];                           // k = 0..191 in registers (384 VGPRs)
  #pragma unroll
  for (int g=0; g<4; g++){
    #pragma unroll
    for (int jj=0; jj<24; jj++) w[g][jj] = wpd[(g*32 + jj)*256 + u];
    #pragma unroll
    for (int jj=24; jj<32; jj++) lwt[g][jj-24][u] = wpd[(g*32 + jj)*256 + u];
  }
  const float* bias = dir ? bbp : bfp;
  float bia[4];
  #pragma unroll
  for (int g=0;g<4;g++) bia[g] = bias[g*256+u];
  lh[0][u] = (f16)0.0f;
  lh[1][u] = (f16)0.0f;
  float c = 0.0f;
  const f16* gxc = gx + (size_t)(b*512)*2048 + dir*1024 + u;
  f16* Hcc = Hc + (size_t)(b*512)*512 + dir*256 + u;
  __syncthreads();
  // prefetch gx for t=0
  f16 gv0, gv1, gv2, gv3;
  {
    int s0 = dir ? 511 : 0;
    const f16* gp = gxc + (size_t)s0*2048;
    gv0 = gp[0]; gv1 = gp[256]; gv2 = gp[512]; gv3 = gp[768];
  }
  for (int t=0; t<512; t++){
    int s = dir ? (511-t) : t;
    int cur = t & 1;
    float acc0 = bia[0] + (float)gv0;
    float acc1 = bia[1] + (float)gv1;
    float acc2 = bia[2] + (float)gv2;
    float acc3 = bia[3] + (float)gv3;
    // prefetch next step's gx (hidden under the dot burst)
    int tn = (t < 511) ? t+1 : 511;
    int sn = dir ? (511 - tn) : tn;
    const f16* gn = gxc + (size_t)sn*2048;
    f16 n0 = gn[0], n1 = gn[256], n2 = gn[512], n3 = gn[768];
    // dot burst: 4 gate rows x K=256, f16 dot2 with fp32 accum
    #pragma unroll
    for (int jj=0; jj<24; jj++){
      u32x4 hh = *(const u32x4*)&lh[cur][jj*8];
      #pragma unroll
      for (int q=0;q<4;q++){
        acc0 = dot2u(w[0][jj][q], hh[q], acc0);
        acc1 = dot2u(w[1][jj][q], hh[q], acc1);
        acc2 = dot2u(w[2][jj][q], hh[q], acc2);
        acc3 = dot2u(w[3][jj][q], hh[q], acc3);
      }
    }
    #pragma unroll
    for (int jj=24; jj<32; jj++){
      u32x4 hh = *(const u32x4*)&lh[cur][jj*8];
      u32x4 w0 = lwt[0][jj-24][u];
      u32x4 w1 = lwt[1][jj-24][u];
      u32x4 w2 = lwt[2][jj-24][u];
      u32x4 w3 = lwt[3][jj-24][u];
      #pragma unroll
      for (int q=0;q<4;q++){
        acc0 = dot2u(w0[q], hh[q], acc0);
        acc1 = dot2u(w1[q], hh[q], acc1);
        acc2 = dot2u(w2[q], hh[q], acc2);
        acc3 = dot2u(w3[q], hh[q], acc3);
      }
    }
    float ig = sigm(acc0), fg = sigm(acc1);
    float gg = tanh_(acc2), og = sigm(acc3);
    c = fg*c + ig*gg;
    float h = og*tanh_(c);
    f16 hf = (f16)h;
    lh[cur^1][u] = hf;
    Hcc[(size_t)s*512] = hf;
    gv0=n0; gv1=n1; gv2=n2; gv3=n3;
    __syncthreads();   // protects lh double-buffer rotation
  }
}

// ---------- K3: emissions e[m][k] = Hcat[m] . Wproj[k] + b_proj[k]  (wave per row) ----------
__global__ __launch_bounds__(256) void k_emis(const f16* __restrict__ Hc,
                 const f16* __restrict__ Wp, const float* __restrict__ bp,
                 float* __restrict__ e){
  int w = threadIdx.x >> 6, l = threadIdx.x & 63;
  int m = blockIdx.x*4 + w;
  f16x8 hv = *(const f16x8*)(Hc + (size_t)m*512 + l*8);
  u32x4 hu = __builtin_bit_cast(u32x4, hv);
  #pragma unroll
  for (int k=0;k<9;k++){
    f16x8 wv = *(const f16x8*)(Wp + k*512 + l*8);
    u32x4 wu = __builtin_bit_cast(u32x4, wv);
    float p = 0.f;
    #pragma unroll
    for (int q=0;q<4;q++) p = dot2u(hu[q], wu[q], p);
    #pragma unroll
    for (int off=32; off; off>>=1) p += __shfl_xor(p, off);
    if (l == k) e[(size_t)m*9 + k] = p + bp[k];
  }
}

// ---------- K4: CRF negative-llh pieces per batch (1 wave per batch) ----------
__global__ void k_crf(const float* __restrict__ e, const int* __restrict__ tags,
                      const int* __restrict__ mask, const float* __restrict__ st,
                      const float* __restrict__ en, const float* __restrict__ tr,
                      float* __restrict__ llh){
  int b = blockIdx.x;
  int l = threadIdx.x;
  int j = (l < 9) ? l : 0;
  float Tc[9];
  #pragma unroll
  for (int i=0;i<9;i++) Tc[i] = tr[i*9 + j];
  const float* eb = e + (size_t)b*512*9;
  const int* tb = tags + b*512;
  const int* mb = mask + b*512;
  float a = st[j] + eb[j];
  int t0 = tb[0];
  float num = st[t0] + eb[t0];
  int prev = t0;
  int cnt = (mb[0] != 0) ? 1 : 0;
  for (int s=1; s<512; s++){
    float ej = eb[s*9 + j];
    float vi[9];
    #pragma unroll
    for (int i=0;i<9;i++) vi[i] = __shfl(a, i) + Tc[i];
    float mx = vi[0];
    #pragma unroll
    for (int i=1;i<9;i++) mx = fmaxf(mx, vi[i]);
    float ssum = 0.f;
    #pragma unroll
    for (int i=0;i<9;i++) ssum += expf(vi[i]-mx);
    float anew = ej + mx + logf(ssum);
    int mt = mb[s];
    a = (mt != 0) ? anew : a;
    int tg = tb[s];
    num += (float)mt * (tr[prev*9+tg] + eb[s*9+tg]);
    prev = tg;
    cnt += (mt != 0) ? 1 : 0;
  }
  // logZ = LSE(alpha + end)
  float av[9];
  #pragma unroll
  for (int i=0;i<9;i++) av[i] = __shfl(a, i) + en[i];
  float mx = av[0];
  #pragma unroll
  for (int i=1;i<9;i++) mx = fmaxf(mx, av[i]);
  float ssum = 0.f;
  #pragma unroll
  for (int i=0;i<9;i++) ssum += expf(av[i]-mx);
  float logZ = mx + logf(ssum);
  if (l == 0){
    int lastt = tb[cnt-1];
    llh[b] = (num + en[lastt]) - logZ;
  }
}

// ---------- K5: final reduce ----------
__global__ void k_red(const float* __restrict__ llh, float* __restrict__ out){
  if (threadIdx.x == 0){
    float s = 0.f;
    for (int i=0;i<64;i++) s += llh[i];
    out[0] = -s / 64.0f;
  }
}

extern "C" void kernel_launch(void* const* d_in, const int* in_sizes, int n_in,
                              void* d_out, int out_size, void* d_ws, size_t ws_size,
                              hipStream_t stream){
  const float* emb  = (const float*)d_in[0];
  const int*   tags = (const int*)d_in[1];
  const int*   mask = (const int*)d_in[2];
  const float* wihf = (const float*)d_in[3];
  const float* whhf = (const float*)d_in[4];
  const float* bfp  = (const float*)d_in[5];
  const float* wihb = (const float*)d_in[6];
  const float* whhb = (const float*)d_in[7];
  const float* bbp  = (const float*)d_in[8];
  const float* wprj = (const float*)d_in[9];
  const float* bprj = (const float*)d_in[10];
  const float* st   = (const float*)d_in[11];
  const float* en   = (const float*)d_in[12];
  const float* tr   = (const float*)d_in[13];

  char* ws = (char*)d_ws;
  f16*   Xf    = (f16*)(ws + 0);                 // 50,331,648 B (aliased by Hc later)
  f16*   Wcat  = (f16*)(ws + 50331648);          //  3,145,728 B
  u32x4* Wpack = (u32x4*)(ws + 53477376);        //  1,048,576 B
  f16*   Wpj   = (f16*)(ws + 54525952);          //      9,216 B
  f16*   gx    = (f16*)(ws + 54535168);          // 134,217,728 B
  float* e     = (float*)(ws + 188752896);       //  1,179,648 B
  float* llh   = (float*)(ws + 189932544);       //        256 B
  f16*   Hc    = Xf;   // safe alias: X only read by k_gemm, which precedes k_rnn

  hipLaunchKernelGGL(k_cvt,   dim3(12288), dim3(256), 0, stream, emb,  Xf, 25165824);
  hipLaunchKernelGGL(k_cvt,   dim3(384),   dim3(256), 0, stream, wihf, Wcat,          786432);
  hipLaunchKernelGGL(k_cvt,   dim3(384),   dim3(256), 0, stream, wihb, Wcat + 786432, 786432);
  hipLaunchKernelGGL(k_cvt,   dim3(3),     dim3(256), 0, stream, wprj, Wpj, 4608);
  hipLaunchKernelGGL(k_wpack, dim3(256),   dim3(256), 0, stream, whhf, whhb, Wpack);
  hipLaunchKernelGGL(k_gemm,  dim3(4096),  dim3(256), 0, stream, Xf, Wcat, gx);
  hipLaunchKernelGGL(k_rnn,   dim3(128),   dim3(256), 0, stream, Wpack, gx, bfp, bbp, Hc);
  hipLaunchKernelGGL(k_emis,  dim3(8192),  dim3(256), 0, stream, Hc, Wpj, bprj, e);
  hipLaunchKernelGGL(k_crf,   dim3(64),    dim3(64),  0, stream, e, tags, mask, st, en, tr, llh);
  hipLaunchKernelGGL(k_red,   dim3(1),     dim3(64),  0, stream, llh, (float*)d_out);
}

// Round 2
// 1293.078 us; speedup vs baseline: 1.6064x; 1.6064x over previous
//
#include <hip/hip_runtime.h>

typedef _Float16 f16;
typedef _Float16 f16x2 __attribute__((ext_vector_type(2)));
typedef _Float16 f16x8 __attribute__((ext_vector_type(8)));
typedef float    f32x4 __attribute__((ext_vector_type(4)));
typedef unsigned int u32x4 __attribute__((ext_vector_type(4)));

// ---------- helpers ----------
__device__ __forceinline__ float dot2u(unsigned a, unsigned b, float c){
  return __builtin_amdgcn_fdot2(__builtin_bit_cast(f16x2, a),
                                __builtin_bit_cast(f16x2, b), c, false);
}
__device__ __forceinline__ float sigm(float x){ return 1.0f/(1.0f+__expf(-x)); }
__device__ __forceinline__ float tanh_(float x){
  x = fminf(fmaxf(x, -20.f), 20.f);
  return 1.0f - 2.0f/(__expf(2.0f*x)+1.0f);
}

// ---------- K0: fp32 -> f16 convert (8 elems/thread) ----------
__global__ void k_cvt(const float* __restrict__ src, f16* __restrict__ dst, int n){
  int i = (blockIdx.x*256 + threadIdx.x)*8;
  if (i >= n) return;
  float4 a = *(const float4*)(src + i);
  float4 b = *(const float4*)(src + i + 4);
  f16x8 o;
  o[0]=(f16)a.x; o[1]=(f16)a.y; o[2]=(f16)a.z; o[3]=(f16)a.w;
  o[4]=(f16)b.x; o[5]=(f16)b.y; o[6]=(f16)b.z; o[7]=(f16)b.w;
  *(f16x8*)(dst+i) = o;
}

// ---------- K0c: pack W_hh into [dir][gl*32+jj][gp*256+u] u32x4 layout ----------
// thread tid=(gp,u) of k_rnn reads wp2[(dir*64 + gl*32 + jj)*512 + tid]
// covering gate G = gp*2+gl, unit u, k = 8*jj..8*jj+7
__global__ void k_wpack2(const float* __restrict__ whf, const float* __restrict__ whb,
                         u32x4* __restrict__ wp){
  int idx = blockIdx.x*256 + threadIdx.x;     // 0..65535
  int t   = idx & 511;
  int p   = (idx >> 9) & 63;
  int dir = (idx >> 15) & 1;
  int u   = t & 255;
  int gp  = t >> 8;
  int jj  = p & 31;
  int gl  = p >> 5;
  int G   = gp*2 + gl;
  const float* w = dir ? whb : whf;
  const float* row = w + (G*256 + u)*256 + jj*8;
  u32x4 v;
  #pragma unroll
  for (int q=0;q<4;q++){
    f16x2 h2; h2[0] = (f16)row[2*q]; h2[1] = (f16)row[2*q+1];
    v[q] = __builtin_bit_cast(unsigned, h2);
  }
  wp[idx] = v;
}

// ---------- K1: gx = X(32768x768) @ Wcat(2048x768)^T  (f16 out, fp32 acc MFMA) ----------
__global__ __launch_bounds__(256) void k_gemm(const f16* __restrict__ A,
                                              const f16* __restrict__ Bw,
                                              f16* __restrict__ C){
  __shared__ alignas(16) f16 As[128][64];
  __shared__ alignas(16) f16 Bs[128][64];
  int bid = blockIdx.x;
  int bm = bid >> 4, bn = bid & 15;
  int tid = threadIdx.x;
  int w = tid >> 6, l = tid & 63;
  int wm = w >> 1, wn = w & 1;
  f32x4 acc[4][4] = {};
  int srow = tid >> 3;
  int scol = (tid & 7)*8;
  const f16* Ag = A  + (size_t)(bm*128)*768 + scol;
  const f16* Bg = Bw + (size_t)(bn*128)*768 + scol;
  int fr = l & 15, kg = l >> 4;
  for (int k0 = 0; k0 < 768; k0 += 64){
    #pragma unroll
    for (int q=0;q<4;q++){
      int rr = srow + 32*q;
      u32x4 av = *(const u32x4*)(Ag + rr*768 + k0);
      u32x4 bv = *(const u32x4*)(Bg + rr*768 + k0);
      *(u32x4*)&As[rr][scol] = av;
      *(u32x4*)&Bs[rr][scol] = bv;
    }
    __syncthreads();
    #pragma unroll
    for (int ks=0; ks<2; ks++){
      f16x8 af[4], bf[4];
      #pragma unroll
      for (int mi=0;mi<4;mi++) af[mi] = *(const f16x8*)&As[wm*64+mi*16+fr][ks*32+kg*8];
      #pragma unroll
      for (int ni=0;ni<4;ni++) bf[ni] = *(const f16x8*)&Bs[wn*64+ni*16+fr][ks*32+kg*8];
      #pragma unroll
      for (int mi=0;mi<4;mi++)
        #pragma unroll
        for (int ni=0;ni<4;ni++)
          acc[mi][ni] = __builtin_amdgcn_mfma_f32_16x16x32_f16(af[mi], bf[ni], acc[mi][ni], 0,0,0);
    }
    __syncthreads();
  }
  int fq = l >> 4;
  #pragma unroll
  for (int mi=0;mi<4;mi++)
    #pragma unroll
    for (int ni=0;ni<4;ni++){
      int mrow = bm*128 + wm*64 + mi*16 + fq*4;
      int ncol = bn*128 + wn*64 + ni*16 + fr;
      #pragma unroll
      for (int r=0;r<4;r++)
        C[(size_t)(mrow+r)*2048 + ncol] = (f16)acc[mi][ni][r];
    }
}

// ---------- K2: recurrence. One block per chain; 512 thr = (gate-pair, unit) ----------
// gp=0 owns gates {i,f} for unit u, gp=1 owns {g,o}. 50 u32x4 weights in VGPR,
// 14 in LDS tail. 8 waves/block = 2 waves/SIMD.
__global__ __launch_bounds__(512,2) void k_rnn(const u32x4* __restrict__ wp,
            const f16* __restrict__ gx, const float* __restrict__ bfp,
            const float* __restrict__ bbp, f16* __restrict__ Hc){
  __shared__ u32x4 lwt[2][7][512];            // 112 KB weight tail (jj = 25..31)
  __shared__ alignas(16) f16 lh[2][256];      // h double buffer
  __shared__ float pacc[2][256];              // g/o partial accs from gp=1
  int chain = blockIdx.x;
  int b = chain >> 1, dir = chain & 1;
  int tid = threadIdx.x;
  int gp = tid >> 8, u = tid & 255;
  const u32x4* wpd = wp + dir*64*512;
  u32x4 w[2][25];                             // jj = 0..24 in registers (200 VGPRs)
  #pragma unroll
  for (int gl=0; gl<2; gl++){
    #pragma unroll
    for (int jj=0; jj<25; jj++) w[gl][jj] = wpd[(gl*32 + jj)*512 + tid];
    #pragma unroll
    for (int jj=25; jj<32; jj++) lwt[gl][jj-25][tid] = wpd[(gl*32 + jj)*512 + tid];
  }
  const float* bias = dir ? bbp : bfp;
  int G0 = gp*2, G1 = gp*2 + 1;
  float bia0 = bias[G0*256+u];
  float bia1 = bias[G1*256+u];
  if (gp == 0) lh[0][u] = (f16)0.0f;
  float c = 0.0f;
  const f16* gxc = gx + (size_t)(b*512)*2048 + dir*1024;
  int o0 = G0*256 + u, o1 = G1*256 + u;
  f16* Hcc = Hc + (size_t)(b*512)*512 + dir*256 + u;
  __syncthreads();
  // prefetch gx for t=0
  f16 gv0, gv1;
  {
    int s0 = dir ? 511 : 0;
    const f16* gpt = gxc + (size_t)s0*2048;
    gv0 = gpt[o0]; gv1 = gpt[o1];
  }
  for (int t=0; t<512; t++){
    int s = dir ? (511-t) : t;
    int cur = t & 1;
    float acc0 = bia0 + (float)gv0;
    float acc1 = bia1 + (float)gv1;
    // prefetch next step's gx (hidden under the dot burst)
    int tn = (t < 511) ? t+1 : 511;
    int sn = dir ? (511 - tn) : tn;
    const f16* gn = gxc + (size_t)sn*2048;
    f16 n0 = gn[o0], n1 = gn[o1];
    // dot burst: 2 gate rows x K=256, f16 dot2 with fp32 accum
    #pragma unroll
    for (int jj=0; jj<25; jj++){
      u32x4 hh = *(const u32x4*)&lh[cur][jj*8];
      #pragma unroll
      for (int q=0;q<4;q++){
        acc0 = dot2u(w[0][jj][q], hh[q], acc0);
        acc1 = dot2u(w[1][jj][q], hh[q], acc1);
      }
    }
    #pragma unroll
    for (int jj=25; jj<32; jj++){
      u32x4 hh = *(const u32x4*)&lh[cur][jj*8];
      u32x4 w0 = lwt[0][jj-25][tid];
      u32x4 w1 = lwt[1][jj-25][tid];
      #pragma unroll
      for (int q=0;q<4;q++){
        acc0 = dot2u(w0[q], hh[q], acc0);
        acc1 = dot2u(w1[q], hh[q], acc1);
      }
    }
    if (gp == 1){ pacc[0][u] = acc0; pacc[1][u] = acc1; }
    __syncthreads();
    if (gp == 0){
      float ig = sigm(acc0), fg = sigm(acc1);
      float gg = tanh_(pacc[0][u]), og = sigm(pacc[1][u]);
      c = fg*c + ig*gg;
      float h = og*tanh_(c);
      f16 hf = (f16)h;
      lh[cur^1][u] = hf;
      Hcc[(size_t)s*512] = hf;
    }
    gv0 = n0; gv1 = n1;
    __syncthreads();   // lh[cur^1] visible to all for next step
  }
}

// ---------- K3: emissions e[m][k] = Hcat[m] . Wproj[k] + b_proj[k]  (wave per row) ----------
__global__ __launch_bounds__(256) void k_emis(const f16* __restrict__ Hc,
                 const f16* __restrict__ Wp, const float* __restrict__ bp,
                 float* __restrict__ e){
  int w = threadIdx.x >> 6, l = threadIdx.x & 63;
  int m = blockIdx.x*4 + w;
  f16x8 hv = *(const f16x8*)(Hc + (size_t)m*512 + l*8);
  u32x4 hu = __builtin_bit_cast(u32x4, hv);
  #pragma unroll
  for (int k=0;k<9;k++){
    f16x8 wv = *(const f16x8*)(Wp + k*512 + l*8);
    u32x4 wu = __builtin_bit_cast(u32x4, wv);
    float p = 0.f;
    #pragma unroll
    for (int q=0;q<4;q++) p = dot2u(hu[q], wu[q], p);
    #pragma unroll
    for (int off=32; off; off>>=1) p += __shfl_xor(p, off);
    if (l == k) e[(size_t)m*9 + k] = p + bp[k];
  }
}

// ---------- K4: CRF negative-llh pieces per batch (1 wave per batch) ----------
__global__ void k_crf(const float* __restrict__ e, const int* __restrict__ tags,
                      const int* __restrict__ mask, const float* __restrict__ st,
                      const float* __restrict__ en, const float* __restrict__ tr,
                      float* __restrict__ llh){
  int b = blockIdx.x;
  int l = threadIdx.x;
  int j = (l < 9) ? l : 0;
  float Tc[9];
  #pragma unroll
  for (int i=0;i<9;i++) Tc[i] = tr[i*9 + j];
  const float* eb = e + (size_t)b*512*9;
  const int* tb = tags + b*512;
  const int* mb = mask + b*512;
  float a = st[j] + eb[j];
  int t0 = tb[0];
  float num = st[t0] + eb[t0];
  int prev = t0;
  int cnt = (mb[0] != 0) ? 1 : 0;
  for (int s=1; s<512; s++){
    float ej = eb[s*9 + j];
    float vi[9];
    #pragma unroll
    for (int i=0;i<9;i++) vi[i] = __shfl(a, i) + Tc[i];
    float mx = vi[0];
    #pragma unroll
    for (int i=1;i<9;i++) mx = fmaxf(mx, vi[i]);
    float ssum = 0.f;
    #pragma unroll
    for (int i=0;i<9;i++) ssum += expf(vi[i]-mx);
    float anew = ej + mx + logf(ssum);
    int mt = mb[s];
    a = (mt != 0) ? anew : a;
    int tg = tb[s];
    num += (float)mt * (tr[prev*9+tg] + eb[s*9+tg]);
    prev = tg;
    cnt += (mt != 0) ? 1 : 0;
  }
  // logZ = LSE(alpha + end)
  float av[9];
  #pragma unroll
  for (int i=0;i<9;i++) av[i] = __shfl(a, i) + en[i];
  float mx = av[0];
  #pragma unroll
  for (int i=1;i<9;i++) mx = fmaxf(mx, av[i]);
  float ssum = 0.f;
  #pragma unroll
  for (int i=0;i<9;i++) ssum += expf(av[i]-mx);
  float logZ = mx + logf(ssum);
  if (l == 0){
    int lastt = tb[cnt-1];
    llh[b] = (num + en[lastt]) - logZ;
  }
}

// ---------- K5: final reduce ----------
__global__ void k_red(const float* __restrict__ llh, float* __restrict__ out){
  if (threadIdx.x == 0){
    float s = 0.f;
    for (int i=0;i<64;i++) s += llh[i];
    out[0] = -s / 64.0f;
  }
}

extern "C" void kernel_launch(void* const* d_in, const int* in_sizes, int n_in,
                              void* d_out, int out_size, void* d_ws, size_t ws_size,
                              hipStream_t stream){
  const float* emb  = (const float*)d_in[0];
  const int*   tags = (const int*)d_in[1];
  const int*   mask = (const int*)d_in[2];
  const float* wihf = (const float*)d_in[3];
  const float* whhf = (const float*)d_in[4];
  const float* bfp  = (const float*)d_in[5];
  const float* wihb = (const float*)d_in[6];
  const float* whhb = (const float*)d_in[7];
  const float* bbp  = (const float*)d_in[8];
  const float* wprj = (const float*)d_in[9];
  const float* bprj = (const float*)d_in[10];
  const float* st   = (const float*)d_in[11];
  const float* en   = (const float*)d_in[12];
  const float* tr   = (const float*)d_in[13];

  char* ws = (char*)d_ws;
  f16*   Xf    = (f16*)(ws + 0);                 // 50,331,648 B (aliased by Hc later)
  f16*   Wcat  = (f16*)(ws + 50331648);          //  3,145,728 B
  u32x4* Wpack = (u32x4*)(ws + 53477376);        //  1,048,576 B
  f16*   Wpj   = (f16*)(ws + 54525952);          //      9,216 B
  f16*   gx    = (f16*)(ws + 54535168);          // 134,217,728 B
  float* e     = (float*)(ws + 188752896);       //  1,179,648 B
  float* llh   = (float*)(ws + 189932544);       //        256 B
  f16*   Hc    = Xf;   // safe alias: X only read by k_gemm, which precedes k_rnn

  hipLaunchKernelGGL(k_cvt,    dim3(12288), dim3(256), 0, stream, emb,  Xf, 25165824);
  hipLaunchKernelGGL(k_cvt,    dim3(384),   dim3(256), 0, stream, wihf, Wcat,          786432);
  hipLaunchKernelGGL(k_cvt,    dim3(384),   dim3(256), 0, stream, wihb, Wcat + 786432, 786432);
  hipLaunchKernelGGL(k_cvt,    dim3(3),     dim3(256), 0, stream, wprj, Wpj, 4608);
  hipLaunchKernelGGL(k_wpack2, dim3(256),   dim3(256), 0, stream, whhf, whhb, Wpack);
  hipLaunchKernelGGL(k_gemm,   dim3(4096),  dim3(256), 0, stream, Xf, Wcat, gx);
  hipLaunchKernelGGL(k_rnn,    dim3(128),   dim3(512), 0, stream, Wpack, gx, bfp, bbp, Hc);
  hipLaunchKernelGGL(k_emis,   dim3(8192),  dim3(256), 0, stream, Hc, Wpj, bprj, e);
  hipLaunchKernelGGL(k_crf,    dim3(64),    dim3(64),  0, stream, e, tags, mask, st, en, tr, llh);
  hipLaunchKernelGGL(k_red,    dim3(1),     dim3(64),  0, stream, llh, (float*)d_out);
}